// Round 3
// baseline (304.816 us; speedup 1.0000x reference)
//
#include <hip/hip_runtime.h>

#define NUM_GRAPHS 512
#define N_NODES 100000
#define N_EDGES 1600000
#define D_NODE 128
#define D_EDGE 32
#define D_OUT 64

#define NB_EDGE 512        // one 64KB LDS histogram per block; exactly 2 blocks/CU
#define EB_THREADS 1024    // 16 waves/block -> 32 waves/CU
#define HIST (NUM_GRAPHS * D_EDGE)   // 16384 floats = 64 KB

// ---------------- kernel 0: eg[e] = batch[col[e]] (streaming, int4) -------------------
__global__ __launch_bounds__(256) void eg_kernel(const int* __restrict__ col,
                                                 const int* __restrict__ batch,
                                                 int* __restrict__ eg) {
    const int i = (blockIdx.x * 256 + threadIdx.x) * 4;
    if (i + 3 < N_EDGES) {
        int4 c = *reinterpret_cast<const int4*>(col + i);
        int g0 = batch[c.x];     // independent gathers, batch is L2-resident (400 KB)
        int g1 = batch[c.y];
        int g2 = batch[c.z];
        int g3 = batch[c.w];
        *reinterpret_cast<int4*>(eg + i) = make_int4(g0, g1, g2, g3);
    }
}

// ---------------- kernel 1: node aggregate (batch sorted -> binary search, float4) ----
__global__ __launch_bounds__(512) void node_agg_kernel(const float* __restrict__ x,
                                                       const int* __restrict__ batch,
                                                       float* __restrict__ node_agg) {
    const int g = blockIdx.x;
    int l = 0, r = N_NODES;
    while (l < r) { int m = (l + r) >> 1; if (batch[m] < g) l = m + 1; else r = m; }
    const int lo = l;
    r = N_NODES;
    while (l < r) { int m = (l + r) >> 1; if (batch[m] < g + 1) l = m + 1; else r = m; }
    const int hi = l;

    const int t = threadIdx.x;
    const int d4 = t & 31;   // float4 column (32 * 4 = 128 floats)
    const int rr = t >> 5;   // 0..15 row phase
    const float4* x4 = reinterpret_cast<const float4*>(x);

    float4 a = make_float4(0.f, 0.f, 0.f, 0.f);
    for (int i = lo + rr; i < hi; i += 16) {
        float4 v = x4[(size_t)i * 32 + d4];
        a.x += v.x; a.y += v.y; a.z += v.z; a.w += v.w;
    }

    __shared__ float4 red[512];
    red[t] = a;
    __syncthreads();
    if (t < 32) {
        float4 s = red[t];
        #pragma unroll
        for (int p = 1; p < 16; ++p) {
            float4 v = red[p * 32 + t];
            s.x += v.x; s.y += v.y; s.z += v.z; s.w += v.w;
        }
        reinterpret_cast<float4*>(node_agg)[g * 32 + t] = s;
    }
}

// ---------------- kernel 2: edge partial histograms (float4, LDS-privatized) ----------
// thread (sub, dq): sub = edge slot (128/block-iter), dq = float4 column of edge_attr row.
// Per wave: 8 edges x 1KB contiguous edge_attr per load instruction.
__global__ __launch_bounds__(EB_THREADS, 8) void edge_partial_kernel(
        const float* __restrict__ edge_attr,
        const int* __restrict__ eg,
        float* __restrict__ part) {
    __shared__ float acc[HIST];   // 64 KB
    const int t = threadIdx.x;
    float4* acc4 = reinterpret_cast<float4*>(acc);
    for (int i = t; i < HIST / 4; i += EB_THREADS) acc4[i] = make_float4(0.f, 0.f, 0.f, 0.f);
    __syncthreads();

    const int sub = t >> 3;            // 0..127
    const int dq  = t & 7;             // 0..7
    const int EPG = EB_THREADS / 8;    // 128 edges per block-iteration
    const int ngrp = N_EDGES / EPG;    // 12500 exactly
    const int chunk = (ngrp + NB_EDGE - 1) / NB_EDGE;   // 25
    const int gbeg = blockIdx.x * chunk;
    const int gend = min(ngrp, gbeg + chunk);
    const float4* ea4 = reinterpret_cast<const float4*>(edge_attr);

    int grp = gbeg;
    for (; grp + 4 <= gend; grp += 4) {
        const int e0 = (grp + 0) * EPG + sub;
        const int e1 = e0 + EPG, e2 = e1 + EPG, e3 = e2 + EPG;
        // 8 independent loads in flight
        const int g0 = eg[e0], g1 = eg[e1], g2 = eg[e2], g3 = eg[e3];
        const float4 v0 = ea4[(size_t)e0 * 8 + dq];
        const float4 v1 = ea4[(size_t)e1 * 8 + dq];
        const float4 v2 = ea4[(size_t)e2 * 8 + dq];
        const float4 v3 = ea4[(size_t)e3 * 8 + dq];
        const int b0 = g0 * D_EDGE + dq * 4;
        const int b1 = g1 * D_EDGE + dq * 4;
        const int b2 = g2 * D_EDGE + dq * 4;
        const int b3 = g3 * D_EDGE + dq * 4;
        // ds_add_f32 has no return value -> no wave stall; 8-way bank alias absorbed by LDS pipe headroom
        atomicAdd(&acc[b0 + 0], v0.x); atomicAdd(&acc[b0 + 1], v0.y);
        atomicAdd(&acc[b0 + 2], v0.z); atomicAdd(&acc[b0 + 3], v0.w);
        atomicAdd(&acc[b1 + 0], v1.x); atomicAdd(&acc[b1 + 1], v1.y);
        atomicAdd(&acc[b1 + 2], v1.z); atomicAdd(&acc[b1 + 3], v1.w);
        atomicAdd(&acc[b2 + 0], v2.x); atomicAdd(&acc[b2 + 1], v2.y);
        atomicAdd(&acc[b2 + 2], v2.z); atomicAdd(&acc[b2 + 3], v2.w);
        atomicAdd(&acc[b3 + 0], v3.x); atomicAdd(&acc[b3 + 1], v3.y);
        atomicAdd(&acc[b3 + 2], v3.z); atomicAdd(&acc[b3 + 3], v3.w);
    }
    for (; grp < gend; ++grp) {
        const int e = grp * EPG + sub;
        const int g = eg[e];
        const float4 v = ea4[(size_t)e * 8 + dq];
        const int b = g * D_EDGE + dq * 4;
        atomicAdd(&acc[b + 0], v.x); atomicAdd(&acc[b + 1], v.y);
        atomicAdd(&acc[b + 2], v.z); atomicAdd(&acc[b + 3], v.w);
    }
    __syncthreads();

    float4* dst = reinterpret_cast<float4*>(part + (size_t)blockIdx.x * HIST);
    for (int i = t; i < HIST / 4; i += EB_THREADS) dst[i] = acc4[i];
}

// ---------------- kernel 3: reduce partials + tiny GEMM -------------------------------
__global__ __launch_bounds__(256) void reduce_gemm_kernel(
        const float* __restrict__ part,
        const float* __restrict__ node_agg,
        const float* __restrict__ W,
        const float* __restrict__ b,
        float* __restrict__ out) {
    const int g = blockIdx.x;
    const int t = threadIdx.x;
    __shared__ float eacc[8][D_EDGE];
    __shared__ float e_final[D_EDGE];
    __shared__ float n_lds[D_NODE];

    const int d = t & 31;
    const int c = t >> 5;                        // 0..7
    float s = 0.f;
    const int PPC = NB_EDGE / 8;                 // 64 partials per chunk
    #pragma unroll 8
    for (int q = 0; q < PPC; ++q) {
        const int p = c * PPC + q;
        s += part[(size_t)p * HIST + g * D_EDGE + d];
    }
    eacc[c][d] = s;
    if (t < D_NODE) n_lds[t] = node_agg[g * D_NODE + t];
    __syncthreads();

    if (t < D_EDGE) {
        float v = 0.f;
        #pragma unroll
        for (int cc = 0; cc < 8; ++cc) v += eacc[cc][t];
        e_final[t] = v;
    }
    __syncthreads();

    if (t < D_OUT) {
        float o = b[t];
        #pragma unroll 8
        for (int k = 0; k < D_NODE; ++k) o += n_lds[k] * W[k * D_OUT + t];
        #pragma unroll 8
        for (int k = 0; k < D_EDGE; ++k) o += e_final[k] * W[(D_NODE + k) * D_OUT + t];
        out[g * D_OUT + t] = o;
    }
}

extern "C" void kernel_launch(void* const* d_in, const int* in_sizes, int n_in,
                              void* d_out, int out_size, void* d_ws, size_t ws_size,
                              hipStream_t stream) {
    const float* x          = (const float*)d_in[0];
    const int*   edge_index = (const int*)d_in[1];
    const float* edge_attr  = (const float*)d_in[2];
    // d_in[3] = u, unused by the reference output
    const int*   batch      = (const int*)d_in[4];
    const float* W          = (const float*)d_in[5];
    const float* b          = (const float*)d_in[6];
    float* out = (float*)d_out;

    const int* col = edge_index + N_EDGES;   // row 1 of edge_index

    // workspace layout
    float* node_agg = (float*)d_ws;                                    // 256 KB
    float* part     = node_agg + (size_t)NUM_GRAPHS * D_NODE;          // 512*64KB = 32 MB
    int*   eg       = (int*)(part + (size_t)NB_EDGE * HIST);           // 6.4 MB

    const int eg_blocks = (N_EDGES / 4 + 255) / 256;                   // 1563
    eg_kernel<<<eg_blocks, 256, 0, stream>>>(col, batch, eg);
    node_agg_kernel<<<NUM_GRAPHS, 512, 0, stream>>>(x, batch, node_agg);
    edge_partial_kernel<<<NB_EDGE, EB_THREADS, 0, stream>>>(edge_attr, eg, part);
    reduce_gemm_kernel<<<NUM_GRAPHS, 256, 0, stream>>>(part, node_agg, W, b, out);
}